// Round 1
// baseline (438.958 us; speedup 1.0000x reference)
//
#include <hip/hip_runtime.h>
#include <hip/hip_bf16.h>

typedef unsigned short u16;
typedef unsigned int u32;

#define N_Q 4096
#define N_M 100000
#define N_M_PAD 100096      // 782 * 128
#define DDIM 128
#define QTILE 128
#define MTILE 128
#define NCHUNK 16
#define NQT (N_Q / QTILE)                    // 32
#define TOTAL_MT (N_M_PAD / MTILE)           // 782
#define TPC ((TOTAL_MT + NCHUNK - 1) / NCHUNK) // 49
#define NSLOT 8                              // contributing lanes per query per (qtile,chunk)
#define NCAND (NCHUNK * NSLOT * 3)           // 384 candidates per query

typedef short bf16x8 __attribute__((ext_vector_type(8)));
typedef float f32x4 __attribute__((ext_vector_type(4)));

// round-to-nearest-even fp32 -> bf16 bits
static __device__ __forceinline__ u16 f2bf(float v) {
  union { float f; u32 u; } a; a.f = v;
  u32 r = a.u + 0x7fffu + ((a.u >> 16) & 1u);
  return (u16)(r >> 16);
}

static __device__ __forceinline__ void async_copy16(const u16* gp, u16* lp) {
  __builtin_amdgcn_global_load_lds(
      (const __attribute__((address_space(1))) u32*)gp,
      (__attribute__((address_space(3))) u32*)lp, 16, 0, 0);
}

// ---------------- kernel 1: L2 norms + bf16 normalized copies ----------------
// one wave per row; rows [0,4096) = queries, [4096, 4096+100096) = memory (pad rows zeroed)
__global__ void knorm(const float* __restrict__ q, const float* __restrict__ m,
                      u16* __restrict__ qn, u16* __restrict__ mn,
                      float* __restrict__ qinv, float* __restrict__ minv) {
  int row = blockIdx.x * 4 + (threadIdx.x >> 6);
  int lane = threadIdx.x & 63;
  const float* src;
  u16* dst;
  int mr = 0;
  bool is_q = (row < N_Q);
  bool pad = false;
  if (is_q) {
    src = q + (size_t)row * DDIM;
    dst = qn + (size_t)row * DDIM;
  } else {
    mr = row - N_Q;
    pad = (mr >= N_M);
    src = m + (size_t)mr * DDIM;
    dst = mn + (size_t)mr * DDIM;
  }
  float2 x;
  if (pad) { x.x = 0.f; x.y = 0.f; }
  else x = ((const float2*)src)[lane];
  float s = x.x * x.x + x.y * x.y;
  #pragma unroll
  for (int off = 1; off < 64; off <<= 1) s += __shfl_xor(s, off, 64);
  float n = sqrtf(s);
  n = fmaxf(n, 1e-12f);
  float invn = 1.0f / n;
  u16 o0 = f2bf(x.x * invn), o1 = f2bf(x.y * invn);
  u32 packed = (u32)o0 | ((u32)o1 << 16);
  ((u32*)dst)[lane] = packed;
  if (lane == 0) {
    if (is_q) qinv[row] = invn;
    else minv[mr] = pad ? 0.f : invn;
  }
}

// ---------------- kernel 2: bf16 MFMA GEMM + streaming per-lane top-3 ----------------
// C[m=memory rows][n=query cols]; per lane: 4 queries (cols), top-3 each in regs.
__global__ __launch_bounds__(256, 2) void kgemm(const u16* __restrict__ qn,
                                                const u16* __restrict__ mn,
                                                float* __restrict__ pval,
                                                int* __restrict__ pidx) {
  __shared__ u16 Bq[QTILE * DDIM];  // 32 KB, queries, swizzled 16B units
  __shared__ u16 Am[MTILE * DDIM];  // 32 KB, memory tile, swizzled

  const int qt = blockIdx.x;   // 0..31
  const int ch = blockIdx.y;   // 0..15
  const int tid = threadIdx.x;
  const int wid = tid >> 6, lane = tid & 63;
  const int quad = lane >> 4, l15 = lane & 15;
  const int wave_m = wid >> 1, wave_q = wid & 1;

  // stage query tile once (rows of qn = cols of C)
  {
    const u16* gbase = qn + (size_t)qt * QTILE * DDIM;
    #pragma unroll
    for (int it = 0; it < 8; ++it) {
      int u = wid * 512 + it * 64 + lane;  // 16B-unit index 0..2047
      int row = u >> 4, su = u & 15;
      int k8 = su ^ (row & 15);
      async_copy16(gbase + row * DDIM + k8 * 8, &Bq[(wid * 512 + it * 64) * 8]);
    }
  }
  __syncthreads();

  const int t0 = ch * TPC;
  const int t1 = (t0 + TPC < TOTAL_MT) ? (t0 + TPC) : TOTAL_MT;

  float tv0[4], tv1[4], tv2[4];
  int ti0[4], ti1[4], ti2[4];
  #pragma unroll
  for (int i = 0; i < 4; ++i) {
    tv0[i] = tv1[i] = tv2[i] = -1e30f;
    ti0[i] = ti1[i] = ti2[i] = 0;
  }

  for (int t = t0; t < t1; ++t) {
    // stage memory tile
    const u16* gbase = mn + (size_t)t * MTILE * DDIM;
    #pragma unroll
    for (int it = 0; it < 8; ++it) {
      int u = wid * 512 + it * 64 + lane;
      int row = u >> 4, su = u & 15;
      int k8 = su ^ (row & 15);
      async_copy16(gbase + row * DDIM + k8 * 8, &Am[(wid * 512 + it * 64) * 8]);
    }
    __syncthreads();

    f32x4 acc[4][4] = {};
    #pragma unroll
    for (int s = 0; s < 4; ++s) {
      const int k8 = (s * 4 + quad) ^ l15;
      bf16x8 a[4], b[4];
      #pragma unroll
      for (int mi = 0; mi < 4; ++mi) {
        int row = wave_m * 64 + mi * 16 + l15;
        a[mi] = *(const bf16x8*)&Am[(row * 16 + k8) * 8];
      }
      #pragma unroll
      for (int ni = 0; ni < 4; ++ni) {
        int col = wave_q * 64 + ni * 16 + l15;
        b[ni] = *(const bf16x8*)&Bq[(col * 16 + k8) * 8];
      }
      #pragma unroll
      for (int mi = 0; mi < 4; ++mi)
        #pragma unroll
        for (int ni = 0; ni < 4; ++ni)
          acc[mi][ni] = __builtin_amdgcn_mfma_f32_16x16x32_bf16(a[mi], b[ni], acc[mi][ni], 0, 0, 0);
    }
    __syncthreads();  // Am consumed; next iter may overwrite

    // epilogue: per-lane top-3 streaming update (register-only)
    const int mbase = t * MTILE + wave_m * 64 + quad * 4;
    #pragma unroll
    for (int ni = 0; ni < 4; ++ni) {
      float bm = -1e30f;
      #pragma unroll
      for (int mi = 0; mi < 4; ++mi) {
        bm = fmaxf(bm, fmaxf(fmaxf(acc[mi][ni][0], acc[mi][ni][1]),
                             fmaxf(acc[mi][ni][2], acc[mi][ni][3])));
      }
      if (bm > tv2[ni]) {  // rare path
        #pragma unroll
        for (int mi = 0; mi < 4; ++mi) {
          #pragma unroll
          for (int r = 0; r < 4; ++r) {
            float x = acc[mi][ni][r];
            int xi = mbase + mi * 16 + r;
            if (x > tv2[ni] && xi < N_M) {
              if (x > tv1[ni]) {
                tv2[ni] = tv1[ni]; ti2[ni] = ti1[ni];
                if (x > tv0[ni]) {
                  tv1[ni] = tv0[ni]; ti1[ni] = ti0[ni];
                  tv0[ni] = x; ti0[ni] = xi;
                } else { tv1[ni] = x; ti1[ni] = xi; }
              } else { tv2[ni] = x; ti2[ni] = xi; }
            }
          }
        }
      }
    }
  }

  // write partial top-3: layout [qt][ch][qlocal][slot][3]
  const int slot = wave_m * 4 + quad;  // 0..7
  #pragma unroll
  for (int ni = 0; ni < 4; ++ni) {
    int qlocal = wave_q * 64 + ni * 16 + l15;
    size_t base = ((((size_t)qt * NCHUNK + ch) * QTILE) + qlocal) * (NSLOT * 3) + slot * 3;
    pval[base + 0] = tv0[ni]; pval[base + 1] = tv1[ni]; pval[base + 2] = tv2[ni];
    pidx[base + 0] = ti0[ni]; pidx[base + 1] = ti1[ni]; pidx[base + 2] = ti2[ni];
  }
}

// ---------------- kernel 3: merge candidates, fp32 rescore, emit top-3 ----------------
__global__ void kmerge(const float* __restrict__ pval, const int* __restrict__ pidx,
                       const float* __restrict__ q, const float* __restrict__ mem,
                       const float* __restrict__ qinv, const float* __restrict__ minv,
                       float* __restrict__ out) {
  const int qg = blockIdx.x;  // query id
  const int tid = threadIdx.x;  // 0..127
  const int qt = qg / QTILE, ql = qg % QTILE;

  // each thread owns 3 of the 384 candidates
  float cv[3]; int ci[3];
  #pragma unroll
  for (int j = 0; j < 3; ++j) {
    int c = tid * 3 + j;       // 0..383
    int chn = c / (NSLOT * 3), jj = c % (NSLOT * 3);
    size_t base = ((((size_t)qt * NCHUNK + chn) * QTILE) + ql) * (NSLOT * 3) + jj;
    cv[j] = pval[base];
    ci[j] = pidx[base];
  }

  __shared__ float sv[128];
  __shared__ int si[128];
  __shared__ int seli[8];

  // 8 argmax passes (val desc, idx asc tiebreak)
  for (int pass = 0; pass < 8; ++pass) {
    float bv = -1e31f; int bi = 0x7fffffff;
    #pragma unroll
    for (int j = 0; j < 3; ++j)
      if (cv[j] > bv || (cv[j] == bv && ci[j] < bi)) { bv = cv[j]; bi = ci[j]; }
    sv[tid] = bv; si[tid] = bi;
    __syncthreads();
    for (int off = 64; off; off >>= 1) {
      if (tid < off) {
        if (sv[tid + off] > sv[tid] || (sv[tid + off] == sv[tid] && si[tid + off] < si[tid])) {
          sv[tid] = sv[tid + off]; si[tid] = si[tid + off];
        }
      }
      __syncthreads();
    }
    int w = si[0]; float wv = sv[0];
    if (tid == 0) seli[pass] = w;
    #pragma unroll
    for (int j = 0; j < 3; ++j)
      if (ci[j] == w && cv[j] == wv) cv[j] = -1e31f;  // remove winner
    __syncthreads();
  }

  // exact fp32 rescore of the 8 selected: 16 threads per candidate
  const int c = tid >> 4, g = tid & 15;
  int midx = seli[c];
  const float qi = qinv[qg];
  const float mi = minv[midx];
  const float* qrow = q + (size_t)qg * DDIM;
  const float* mrow = mem + (size_t)midx * DDIM;
  float s = 0.f;
  #pragma unroll
  for (int d = 0; d < 8; ++d) {
    int dd = g * 8 + d;
    s += (qrow[dd] * qi) * (mrow[dd] * mi);
  }
  #pragma unroll
  for (int off = 8; off; off >>= 1) s += __shfl_down(s, off, 16);
  __shared__ float exv[8];
  if (g == 0) exv[c] = s;
  __syncthreads();

  if (tid == 0) {
    float v[8]; int ix[8];
    #pragma unroll
    for (int i = 0; i < 8; ++i) { v[i] = exv[i]; ix[i] = seli[i]; }
    #pragma unroll
    for (int a = 0; a < 3; ++a) {
      int best = a;
      for (int b = a + 1; b < 8; ++b)
        if (v[b] > v[best] || (v[b] == v[best] && ix[b] < ix[best])) best = b;
      float tv = v[a]; v[a] = v[best]; v[best] = tv;
      int tix = ix[a]; ix[a] = ix[best]; ix[best] = tix;
      out[(size_t)qg * 3 + a] = 1.0f - v[a];
      out[(size_t)N_Q * 3 + (size_t)qg * 3 + a] = (float)ix[a];
    }
  }
}

extern "C" void kernel_launch(void* const* d_in, const int* in_sizes, int n_in,
                              void* d_out, int out_size, void* d_ws, size_t ws_size,
                              hipStream_t stream) {
  const float* q = (const float*)d_in[0];
  const float* m = (const float*)d_in[1];
  // d_in[2] is k (=3), fixed at compile time

  char* ws = (char*)d_ws;
  size_t off = 0;
  u16* qn = (u16*)(ws + off); off += (size_t)N_Q * DDIM * 2;        // 1 MB
  u16* mn = (u16*)(ws + off); off += (size_t)N_M_PAD * DDIM * 2;    // 25.6 MB
  float* qinv = (float*)(ws + off); off += (size_t)N_Q * 4;
  float* minv = (float*)(ws + off); off += (size_t)N_M_PAD * 4;
  float* pval = (float*)(ws + off); off += (size_t)NQT * NCHUNK * QTILE * NSLOT * 3 * 4;
  int* pidx = (int*)(ws + off); off += (size_t)NQT * NCHUNK * QTILE * NSLOT * 3 * 4;

  knorm<<<(N_Q + N_M_PAD) / 4, 256, 0, stream>>>(q, m, qn, mn, qinv, minv);
  kgemm<<<dim3(NQT, NCHUNK), 256, 0, stream>>>(qn, mn, pval, pidx);
  kmerge<<<N_Q, 128, 0, stream>>>(pval, pidx, q, m, qinv, minv, (float*)d_out);
}

// Round 2
// 303.935 us; speedup vs baseline: 1.4442x; 1.4442x over previous
//
#include <hip/hip_runtime.h>
#include <hip/hip_bf16.h>

typedef unsigned short u16;
typedef unsigned int u32;

#define N_Q 4096
#define N_M 100000
#define N_M_PAD 100096      // 782 * 128
#define DDIM 128
#define QTILE 128
#define MTILE 128
#define NCHUNK 16
#define NQT (N_Q / QTILE)                    // 32
#define TOTAL_MT (N_M_PAD / MTILE)           // 782
#define TPC ((TOTAL_MT + NCHUNK - 1) / NCHUNK) // 49
#define NSLOT 8
#define NCAND (NCHUNK * NSLOT * 3)           // 384

typedef short bf16x8 __attribute__((ext_vector_type(8)));
typedef float f32x4 __attribute__((ext_vector_type(4)));

static __device__ __forceinline__ u16 f2bf(float v) {
  union { float f; u32 u; } a; a.f = v;
  u32 r = a.u + 0x7fffu + ((a.u >> 16) & 1u);
  return (u16)(r >> 16);
}

static __device__ __forceinline__ void async_copy16(const u16* gp, u16* lp) {
  __builtin_amdgcn_global_load_lds(
      (const __attribute__((address_space(1))) u32*)gp,
      (__attribute__((address_space(3))) u32*)lp, 16, 0, 0);
}

// ---------------- kernel 1: L2 norms + bf16 normalized copies ----------------
__global__ void knorm(const float* __restrict__ q, const float* __restrict__ m,
                      u16* __restrict__ qn, u16* __restrict__ mn,
                      float* __restrict__ qinv, float* __restrict__ minv) {
  int row = blockIdx.x * 4 + (threadIdx.x >> 6);
  int lane = threadIdx.x & 63;
  const float* src;
  u16* dst;
  int mr = 0;
  bool is_q = (row < N_Q);
  bool pad = false;
  if (is_q) {
    src = q + (size_t)row * DDIM;
    dst = qn + (size_t)row * DDIM;
  } else {
    mr = row - N_Q;
    pad = (mr >= N_M);
    src = m + (size_t)mr * DDIM;
    dst = mn + (size_t)mr * DDIM;
  }
  float2 x;
  if (pad) { x.x = 0.f; x.y = 0.f; }
  else x = ((const float2*)src)[lane];
  float s = x.x * x.x + x.y * x.y;
  #pragma unroll
  for (int off = 1; off < 64; off <<= 1) s += __shfl_xor(s, off, 64);
  float n = sqrtf(s);
  n = fmaxf(n, 1e-12f);
  float invn = 1.0f / n;
  u16 o0 = f2bf(x.x * invn), o1 = f2bf(x.y * invn);
  u32 packed = (u32)o0 | ((u32)o1 << 16);
  ((u32*)dst)[lane] = packed;
  if (lane == 0) {
    if (is_q) qinv[row] = invn;
    else minv[mr] = pad ? 0.f : invn;
  }
}

// ---------------- kernel 2 helpers ----------------
static __device__ __forceinline__ void stageA(const u16* __restrict__ mn, u16* dst,
                                              int t, int wid, int lane) {
  const u16* gbase = mn + (size_t)t * MTILE * DDIM;
  #pragma unroll
  for (int it = 0; it < 8; ++it) {
    int u = wid * 512 + it * 64 + lane;
    int row = u >> 4, su = u & 15;
    int k8 = su ^ (row & 15);
    async_copy16(gbase + row * DDIM + k8 * 8, dst + (size_t)(wid * 512 + it * 64) * 8);
  }
}

// branchless sorted insert of (v,i) into descending (t0,t1,t2)
static __device__ __forceinline__ void ins3(float v, int i,
                                            float& a0, float& a1, float& a2,
                                            int& i0, int& i1, int& i2) {
  bool g2 = v > a2, g1 = v > a1, g0 = v > a0;
  a2 = g1 ? a1 : (g2 ? v : a2);
  i2 = g1 ? i1 : (g2 ? i : i2);
  a1 = g0 ? a0 : (g1 ? v : a1);
  i1 = g0 ? i0 : (g1 ? i : i1);
  a0 = g0 ? v : a0;
  i0 = g0 ? i : i0;
}

static __device__ __forceinline__ float max16(const float* p) {
  float m01 = fmaxf(p[0], p[1]),  m23 = fmaxf(p[2], p[3]);
  float m45 = fmaxf(p[4], p[5]),  m67 = fmaxf(p[6], p[7]);
  float m89 = fmaxf(p[8], p[9]),  mab = fmaxf(p[10], p[11]);
  float mcd = fmaxf(p[12], p[13]), mef = fmaxf(p[14], p[15]);
  float q0 = fmaxf(m01, m23), q1 = fmaxf(m45, m67);
  float q2 = fmaxf(m89, mab), q3 = fmaxf(mcd, mef);
  return fmaxf(fmaxf(q0, q1), fmaxf(q2, q3));
}

static __device__ __forceinline__ void tileWork(
    const u16* As, int t, int wave_m, int quad, int l15,
    const bf16x8 (&bq)[4][4],
    float (&tv0)[4], float (&tv1)[4], float (&tv2)[4],
    int (&ti0)[4], int (&ti1)[4], int (&ti2)[4]) {
  f32x4 acc[4][4] = {};  // [mi][ni]
  #pragma unroll
  for (int s = 0; s < 4; ++s) {
    bf16x8 a[4];
    #pragma unroll
    for (int mi = 0; mi < 4; ++mi) {
      int row = wave_m * 64 + mi * 16 + l15;
      int k8 = (s * 4 + quad) ^ l15;
      a[mi] = *(const bf16x8*)&As[(row * 16 + k8) * 8];
    }
    #pragma unroll
    for (int mi = 0; mi < 4; ++mi)
      #pragma unroll
      for (int ni = 0; ni < 4; ++ni)
        acc[mi][ni] = __builtin_amdgcn_mfma_f32_16x16x32_bf16(a[mi], bq[ni][s], acc[mi][ni], 0, 0, 0);
  }
  const int mbase = t * MTILE + wave_m * 64 + quad * 4;
  #pragma unroll
  for (int ni = 0; ni < 4; ++ni) {
    // pack code (mi*16+r, 6 bits) into low mantissa bits: order-preserving
    // perturbation ~2^-18, negligible vs bf16 screen noise; exact fp32 rescore later.
    float p[16];
    #pragma unroll
    for (int mi = 0; mi < 4; ++mi)
      #pragma unroll
      for (int r = 0; r < 4; ++r)
        p[mi * 4 + r] = __uint_as_float(
            (__float_as_uint(acc[mi][ni][r]) & 0xFFFFFFC0u) | (u32)(mi * 16 + r));
    float bm1 = max16(p);
    #pragma unroll
    for (int j = 0; j < 16; ++j) p[j] = (p[j] == bm1) ? -1e30f : p[j];
    float bm2 = max16(p);
    int xi1 = mbase + (int)(__float_as_uint(bm1) & 63u);
    int xi2 = mbase + (int)(__float_as_uint(bm2) & 63u);
    float v1 = (xi1 < N_M) ? bm1 : -1e30f;
    float v2 = (xi2 < N_M) ? bm2 : -1e30f;
    ins3(v1, xi1, tv0[ni], tv1[ni], tv2[ni], ti0[ni], ti1[ni], ti2[ni]);
    ins3(v2, xi2, tv0[ni], tv1[ni], tv2[ni], ti0[ni], ti1[ni], ti2[ni]);
  }
}

// ---------------- kernel 2: MFMA GEMM + streaming per-lane top-3 ----------------
__global__ __launch_bounds__(256, 2) void kgemm(const u16* __restrict__ qn,
                                                const u16* __restrict__ mn,
                                                float* __restrict__ pval,
                                                int* __restrict__ pidx) {
  __shared__ u16 A0[MTILE * DDIM];  // 32 KB
  __shared__ u16 A1[MTILE * DDIM];  // 32 KB (statically distinct for AA)

  const int id = blockIdx.x;                 // 0..511
  const int xcd = id & 7, sub = id >> 3;     // XCD-aware: each XCD sees 2 chunks
  const int ch = xcd * 2 + (sub >> 5);       // 0..15
  const int qt = sub & 31;                   // 0..31
  const int tid = threadIdx.x;
  const int wid = tid >> 6, lane = tid & 63;
  const int quad = lane >> 4, l15 = lane & 15;
  const int wave_m = wid >> 1, wave_q = wid & 1;

  const int t0 = ch * TPC;
  const int t1 = (t0 + TPC < TOTAL_MT) ? (t0 + TPC) : TOTAL_MT;

  // stage first A tile (async) while B fragments load
  stageA(mn, A0, t0, wid, lane);

  // B (query) fragments: loop-invariant, keep in registers (64 VGPRs)
  bf16x8 bq[4][4];  // [ni][s]
  #pragma unroll
  for (int ni = 0; ni < 4; ++ni) {
    int col = qt * QTILE + wave_q * 64 + ni * 16 + l15;
    #pragma unroll
    for (int s = 0; s < 4; ++s)
      bq[ni][s] = *(const bf16x8*)&qn[(size_t)col * DDIM + (s * 4 + quad) * 8];
  }

  float tv0[4], tv1[4], tv2[4];
  int ti0[4], ti1[4], ti2[4];
  #pragma unroll
  for (int i = 0; i < 4; ++i) {
    tv0[i] = tv1[i] = tv2[i] = -1e30f;
    ti0[i] = ti1[i] = ti2[i] = 0;
  }

  __syncthreads();  // A0 staged

  int t = t0;
  while (true) {
    if (t + 1 < t1) stageA(mn, A1, t + 1, wid, lane);   // prefetch overlaps compute
    tileWork(A0, t, wave_m, quad, l15, bq, tv0, tv1, tv2, ti0, ti1, ti2);
    __syncthreads();
    ++t; if (t >= t1) break;
    if (t + 1 < t1) stageA(mn, A0, t + 1, wid, lane);
    tileWork(A1, t, wave_m, quad, l15, bq, tv0, tv1, tv2, ti0, ti1, ti2);
    __syncthreads();
    ++t; if (t >= t1) break;
  }

  // write partial top-3: layout [qt][ch][qlocal][slot][3]
  const int slot = wave_m * 4 + quad;  // 0..7
  #pragma unroll
  for (int ni = 0; ni < 4; ++ni) {
    int qlocal = wave_q * 64 + ni * 16 + l15;
    size_t base = ((((size_t)qt * NCHUNK + ch) * QTILE) + qlocal) * (NSLOT * 3) + slot * 3;
    pval[base + 0] = tv0[ni]; pval[base + 1] = tv1[ni]; pval[base + 2] = tv2[ni];
    pidx[base + 0] = ti0[ni]; pidx[base + 1] = ti1[ni]; pidx[base + 2] = ti2[ni];
  }
}

// ---------------- kernel 3: merge, fp32 rescore, emit top-3 (wave-per-query) ----------------
__global__ __launch_bounds__(256) void kmerge(const float* __restrict__ pval,
                                              const int* __restrict__ pidx,
                                              const float* __restrict__ q,
                                              const float* __restrict__ mem,
                                              const float* __restrict__ qinv,
                                              const float* __restrict__ minv,
                                              float* __restrict__ out) {
  const int tid = threadIdx.x;
  const int wq = tid >> 6;          // wave within block -> query
  const int lane = tid & 63;
  const int qg = blockIdx.x * 4 + wq;
  const int qt = qg >> 7, ql = qg & 127;

  // lane -> 6 of the 384 candidates: chunk = lane>>2, 6 of that chunk's 24
  const int chn = lane >> 2;
  const int jb = (lane & 3) * 6;
  size_t base = ((((size_t)qt * NCHUNK + chn) * QTILE) + ql) * (NSLOT * 3) + jb;
  float cv[6]; int ci[6];
  #pragma unroll
  for (int j = 0; j < 6; ++j) { cv[j] = pval[base + j]; ci[j] = pidx[base + j]; }

  // 8 argmax passes (val desc, idx asc), shuffle-only
  int wi[8];
  #pragma unroll
  for (int pass = 0; pass < 8; ++pass) {
    float bv = cv[0]; int bi = ci[0];
    #pragma unroll
    for (int j = 1; j < 6; ++j) {
      bool g = (cv[j] > bv) || (cv[j] == bv && ci[j] < bi);
      bv = g ? cv[j] : bv; bi = g ? ci[j] : bi;
    }
    #pragma unroll
    for (int off = 32; off >= 1; off >>= 1) {
      float ov = __shfl_xor(bv, off, 64);
      int oi = __shfl_xor(bi, off, 64);
      bool g = (ov > bv) || (ov == bv && oi < bi);
      bv = g ? ov : bv; bi = g ? oi : bi;
    }
    wi[pass] = bi;
    #pragma unroll
    for (int j = 0; j < 6; ++j) if (ci[j] == bi) cv[j] = -1e31f;
  }

  // exact fp32 rescore: 8 lanes per candidate, 16 dims each
  const int g = lane >> 3, r = lane & 7;
  int midx = wi[0];
  #pragma unroll
  for (int p = 1; p < 8; ++p) midx = (g == p) ? wi[p] : midx;
  const float qi = qinv[qg];
  const float mi2 = minv[midx];
  const float* qrow = q + (size_t)qg * DDIM;
  const float* mrow = mem + (size_t)midx * DDIM;
  float s = 0.f;
  #pragma unroll
  for (int d = 0; d < 16; ++d) {
    int dd = r * 16 + d;
    s += (qrow[dd] * qi) * (mrow[dd] * mi2);
  }
  #pragma unroll
  for (int off = 1; off < 8; off <<= 1) s += __shfl_xor(s, off, 64);  // within 8-group

  // move candidate p's exact value to lane p
  float myv = __shfl(s, (lane * 8) & 63, 64);
  int myi = wi[0];
  #pragma unroll
  for (int p = 1; p < 8; ++p) myi = (lane == p) ? wi[p] : myi;
  if (lane >= 8) { myv = -1e31f; myi = 0x7fffffff; }

  // 3 selection passes over the 8 exact values
  #pragma unroll
  for (int a = 0; a < 3; ++a) {
    float bv = myv; int bi = myi;
    #pragma unroll
    for (int off = 32; off >= 1; off >>= 1) {
      float ov = __shfl_xor(bv, off, 64);
      int oi = __shfl_xor(bi, off, 64);
      bool g2 = (ov > bv) || (ov == bv && oi < bi);
      bv = g2 ? ov : bv; bi = g2 ? oi : bi;
    }
    if (lane == 0) {
      out[(size_t)qg * 3 + a] = 1.0f - bv;
      out[(size_t)N_Q * 3 + (size_t)qg * 3 + a] = (float)bi;
    }
    if (myi == bi) myv = -1e31f;
  }
}

extern "C" void kernel_launch(void* const* d_in, const int* in_sizes, int n_in,
                              void* d_out, int out_size, void* d_ws, size_t ws_size,
                              hipStream_t stream) {
  const float* q = (const float*)d_in[0];
  const float* m = (const float*)d_in[1];

  char* ws = (char*)d_ws;
  size_t off = 0;
  u16* qn = (u16*)(ws + off); off += (size_t)N_Q * DDIM * 2;
  u16* mn = (u16*)(ws + off); off += (size_t)N_M_PAD * DDIM * 2;
  float* qinv = (float*)(ws + off); off += (size_t)N_Q * 4;
  float* minv = (float*)(ws + off); off += (size_t)N_M_PAD * 4;
  float* pval = (float*)(ws + off); off += (size_t)NQT * NCHUNK * QTILE * NSLOT * 3 * 4;
  int* pidx = (int*)(ws + off); off += (size_t)NQT * NCHUNK * QTILE * NSLOT * 3 * 4;

  knorm<<<(N_Q + N_M_PAD) / 4, 256, 0, stream>>>(q, m, qn, mn, qinv, minv);
  kgemm<<<NQT * NCHUNK, 256, 0, stream>>>(qn, mn, pval, pidx);
  kmerge<<<N_Q / 4, 256, 0, stream>>>(pval, pidx, q, m, qinv, minv, (float*)d_out);
}

// Round 4
// 283.333 us; speedup vs baseline: 1.5493x; 1.0727x over previous
//
#include <hip/hip_runtime.h>
#include <hip/hip_bf16.h>

typedef unsigned short u16;
typedef unsigned int u32;

#define N_Q 4096
#define N_M 100000
#define N_M_PAD 100096      // 1564 * 64
#define DDIM 128
#define QTILE 128
#define MTILE 64
#define NCHUNK 32
#define NQT (N_Q / QTILE)                      // 32
#define TOTAL_MT (N_M_PAD / MTILE)             // 1564
#define TPC ((TOTAL_MT + NCHUNK - 1) / NCHUNK) // 49
#define NSLOT 8
#define NCAND (NCHUNK * NSLOT * 3)             // 768

typedef short bf16x8 __attribute__((ext_vector_type(8)));
typedef float f32x4 __attribute__((ext_vector_type(4)));

static __device__ __forceinline__ u16 f2bf(float v) {
  union { float f; u32 u; } a; a.f = v;
  u32 r = a.u + 0x7fffu + ((a.u >> 16) & 1u);
  return (u16)(r >> 16);
}

static __device__ __forceinline__ void async_copy16(const u16* gp, u16* lp) {
  __builtin_amdgcn_global_load_lds(
      (const __attribute__((address_space(1))) u32*)gp,
      (__attribute__((address_space(3))) u32*)lp, 16, 0, 0);
}

// ---------------- kernel 1: L2 norms + bf16 normalized copies (grid-stride) ----------------
__global__ __launch_bounds__(256) void knorm(const float* __restrict__ q, const float* __restrict__ m,
                                             u16* __restrict__ qn, u16* __restrict__ mn,
                                             float* __restrict__ qinv, float* __restrict__ minv) {
  const int lane = threadIdx.x & 63;
  const int nw = gridDim.x * 4;
  for (int row = blockIdx.x * 4 + (threadIdx.x >> 6); row < N_Q + N_M_PAD; row += nw) {
    const float* src;
    u16* dst;
    int mr = 0;
    bool is_q = (row < N_Q);
    bool pad = false;
    if (is_q) {
      src = q + (size_t)row * DDIM;
      dst = qn + (size_t)row * DDIM;
    } else {
      mr = row - N_Q;
      pad = (mr >= N_M);
      src = m + (size_t)mr * DDIM;
      dst = mn + (size_t)mr * DDIM;
    }
    float2 x;
    if (pad) { x.x = 0.f; x.y = 0.f; }
    else x = ((const float2*)src)[lane];
    float s = x.x * x.x + x.y * x.y;
    #pragma unroll
    for (int off = 1; off < 64; off <<= 1) s += __shfl_xor(s, off, 64);
    float invn = 1.0f / fmaxf(sqrtf(s), 1e-12f);
    u32 packed = (u32)f2bf(x.x * invn) | ((u32)f2bf(x.y * invn) << 16);
    ((u32*)dst)[lane] = packed;
    if (lane == 0) {
      if (is_q) qinv[row] = invn;
      else minv[mr] = pad ? 0.f : invn;
    }
  }
}

// ---------------- kernel 2 helpers ----------------
static __device__ __forceinline__ void stage4(const u16* __restrict__ mn, u16* dst,
                                              int t, const u32* goff, u32 loff0) {
  const u16* gbase = mn + (size_t)t * MTILE * DDIM;
  #pragma unroll
  for (int it = 0; it < 4; ++it)
    async_copy16(gbase + goff[it], dst + loff0 + (u32)(it * 64) * 8);
}

static __device__ __forceinline__ void tileWork(
    const u16* As, int tl, int wave_m, int quad, int l15,
    const bf16x8 (&bq)[4][4], float (&tv0)[4], float (&tv1)[4], float (&tv2)[4]) {
  f32x4 acc[2][4] = {};  // [mi][ni]
  #pragma unroll
  for (int s = 0; s < 4; ++s) {
    int c = (s * 4 + quad) ^ l15;
    bf16x8 a0 = *(const bf16x8*)&As[((wave_m * 32 + l15) * 16 + c) * 8];
    bf16x8 a1 = *(const bf16x8*)&As[((wave_m * 32 + 16 + l15) * 16 + c) * 8];
    #pragma unroll
    for (int ni = 0; ni < 4; ++ni) {
      acc[0][ni] = __builtin_amdgcn_mfma_f32_16x16x32_bf16(a0, bq[ni][s], acc[0][ni], 0, 0, 0);
      acc[1][ni] = __builtin_amdgcn_mfma_f32_16x16x32_bf16(a1, bq[ni][s], acc[1][ni], 0, 0, 0);
    }
  }
  // epilogue: pack 9-bit local code into low mantissa bits, exact top-2 of 8,
  // branchless sorted-merge into packed top-3 (indices travel inside the floats)
  const u32 tl8 = (u32)tl << 3;  // code = tl*8 + mi*4 + r  (< 392, 9 bits)
  #pragma unroll
  for (int ni = 0; ni < 4; ++ni) {
    float p[8];
    #pragma unroll
    for (int mi = 0; mi < 2; ++mi)
      #pragma unroll
      for (int r = 0; r < 4; ++r)
        p[mi * 4 + r] = __uint_as_float(
            (__float_as_uint(acc[mi][ni][r]) & 0xFFFFFE00u) | (tl8 + (u32)(mi * 4 + r)));
    float h0 = fmaxf(p[0], p[1]), l0 = fminf(p[0], p[1]);
    float h1 = fmaxf(p[2], p[3]), l1 = fminf(p[2], p[3]);
    float h2 = fmaxf(p[4], p[5]), l2 = fminf(p[4], p[5]);
    float h3 = fmaxf(p[6], p[7]), l3 = fminf(p[6], p[7]);
    float ha = fmaxf(h0, h1), la = fmaxf(fminf(h0, h1), fmaxf(l0, l1));
    float hb = fmaxf(h2, h3), lb = fmaxf(fminf(h2, h3), fmaxf(l2, l3));
    float H  = fmaxf(ha, hb), L  = fmaxf(fminf(ha, hb), fmaxf(la, lb));
    float x = fminf(tv0[ni], H);
    tv0[ni] = fmaxf(tv0[ni], H);
    float y = fmaxf(tv1[ni], L);
    float w = fminf(tv1[ni], L);
    tv2[ni] = fmaxf(fminf(x, y), fmaxf(tv2[ni], w));
    tv1[ni] = fmaxf(x, y);
  }
}

// ---------------- kernel 2: bf16 MFMA GEMM + packed streaming top-3 ----------------
// grid 1024 = 32 qtiles x 32 chunks (4 blocks/CU). Waves: 2(m) x 2(q).
__global__ __launch_bounds__(256, 4) void kgemm(const u16* __restrict__ qn,
                                                const u16* __restrict__ mn,
                                                float* __restrict__ pval) {
  __shared__ u16 A0[MTILE * DDIM];  // 16 KB
  __shared__ u16 A1[MTILE * DDIM];  // 16 KB

  const int id = blockIdx.x;                  // 0..1023
  const int xcd = id & 7, sub = id >> 3;      // XCD-aware: 4 chunks per XCD (3.2MB in L2)
  const int ch = xcd * 4 + (sub >> 5);        // 0..31
  const int qt = sub & 31;                    // 0..31
  const int tid = threadIdx.x;
  const int wid = tid >> 6, lane = tid & 63;
  const int quad = lane >> 4, l15 = lane & 15;
  const int wave_m = wid >> 1, wave_q = wid & 1;

  const int t0 = ch * TPC;
  const int t1 = (t0 + TPC < TOTAL_MT) ? (t0 + TPC) : TOTAL_MT;
  const int nt = t1 - t0;

  // precompute staging offsets (4 x 16B units per thread; 1024 units per 64x128 tile)
  u32 goff[4];
  u32 loff0;
  {
    int u0 = wid * 256 + lane;
    loff0 = (u32)(wid * 256) * 8;  // wave-uniform LDS base (HW adds lane*16B)
    #pragma unroll
    for (int it = 0; it < 4; ++it) {
      int u = u0 + it * 64;
      int row = u >> 4, su = u & 15;
      int k8 = su ^ (row & 15);
      goff[it] = (u32)(row * DDIM + k8 * 8);
    }
  }

  // stage first A tile
  stage4(mn, A0, t0, goff, loff0);

  // B (query) fragments: loop-invariant, in registers (64 VGPRs)
  bf16x8 bq[4][4];  // [ni][s]
  #pragma unroll
  for (int ni = 0; ni < 4; ++ni) {
    int col = qt * QTILE + wave_q * 64 + ni * 16 + l15;
    #pragma unroll
    for (int s = 0; s < 4; ++s)
      bq[ni][s] = *(const bf16x8*)&qn[(size_t)col * DDIM + (s * 4 + quad) * 8];
  }

  // packed top-3 per ni (value bits carry 9-bit local code)
  float tv0[4], tv1[4], tv2[4];
  #pragma unroll
  for (int i = 0; i < 4; ++i) { tv0[i] = tv1[i] = tv2[i] = -1e30f; }

  __syncthreads();  // A0 staged

  // two-phase double-buffered loop: A0/A1 referenced statically (no LDS ptr array)
  int tl = 0;
  while (true) {
    if (tl + 1 < nt) stage4(mn, A1, t0 + tl + 1, goff, loff0);
    tileWork(A0, tl, wave_m, quad, l15, bq, tv0, tv1, tv2);
    __syncthreads();
    ++tl; if (tl >= nt) break;
    if (tl + 1 < nt) stage4(mn, A0, t0 + tl + 1, goff, loff0);
    tileWork(A1, tl, wave_m, quad, l15, bq, tv0, tv1, tv2);
    __syncthreads();
    ++tl; if (tl >= nt) break;
  }

  // write packed top-3: layout [qt][ch][qlocal][slot][3], slot = wave_m*4+quad
  const int slot = wave_m * 4 + quad;
  #pragma unroll
  for (int ni = 0; ni < 4; ++ni) {
    int qlocal = wave_q * 64 + ni * 16 + l15;
    size_t base = (((size_t)qt * NCHUNK + ch) * QTILE + qlocal) * (NSLOT * 3) + slot * 3;
    pval[base + 0] = tv0[ni];
    pval[base + 1] = tv1[ni];
    pval[base + 2] = tv2[ni];
  }
}

// decode global memory row from candidate position (0..767) + packed value bits
static __device__ __forceinline__ int decode_row(int pos, float pv) {
  int ch = pos / 24;
  int rem = pos - ch * 24;
  int slot = rem / 3;             // 0..7
  u32 code = __float_as_uint(pv) & 511u;
  int tl = (int)(code >> 3), mi = (int)((code >> 2) & 1u), r = (int)(code & 3u);
  return (ch * TPC + tl) * MTILE + (slot >> 2) * 32 + mi * 16 + (slot & 3) * 4 + r;
}

// ---------------- kernel 3: merge 768 candidates, fp32 rescore top-8, emit top-3 ----------------
__global__ __launch_bounds__(256) void kmerge(const float* __restrict__ pval,
                                              const float* __restrict__ q,
                                              const float* __restrict__ mem,
                                              const float* __restrict__ qinv,
                                              const float* __restrict__ minv,
                                              float* __restrict__ out) {
  const int tid = threadIdx.x;
  const int wq = tid >> 6;
  const int lane = tid & 63;
  const int qg = blockIdx.x * 4 + wq;
  const int qt = qg >> 7, ql = qg & 127;

  // lane owns 12 consecutive candidates: pos = lane*12 + j
  const int chn = lane >> 1;
  size_t base = (((size_t)qt * NCHUNK + chn) * QTILE + ql) * (NSLOT * 3) + (lane & 1) * 12;
  float cv[12];
  #pragma unroll
  for (int j = 0; j < 12; ++j) cv[j] = pval[base + j];

  // 8 argmax passes over packed values (pos tiebreak), shuffle-only
  float wv[8]; int wp[8];
  #pragma unroll
  for (int pass = 0; pass < 8; ++pass) {
    float bv = cv[0]; int bp = lane * 12;
    #pragma unroll
    for (int j = 1; j < 12; ++j) {
      bool g = (cv[j] > bv);
      bv = g ? cv[j] : bv; bp = g ? (lane * 12 + j) : bp;
    }
    #pragma unroll
    for (int off = 32; off >= 1; off >>= 1) {
      float ov = __shfl_xor(bv, off, 64);
      int op = __shfl_xor(bp, off, 64);
      bool g = (ov > bv) || (ov == bv && op < bp);
      bv = g ? ov : bv; bp = g ? op : bp;
    }
    wv[pass] = bv; wp[pass] = bp;
    #pragma unroll
    for (int j = 0; j < 12; ++j)
      if (lane * 12 + j == bp) cv[j] = -1e31f;
  }

  // exact fp32 rescore: 8 lanes per candidate, 16 dims each
  const int g = lane >> 3, r = lane & 7;
  int cpos = wp[0]; float cpv = wv[0];
  #pragma unroll
  for (int p = 1; p < 8; ++p) {
    cpos = (g == p) ? wp[p] : cpos;
    cpv  = (g == p) ? wv[p] : cpv;
  }
  int row = decode_row(cpos, cpv);
  int ra = (row < N_M) ? row : 0;       // pads never win; clamp address anyway
  const float qi = qinv[qg];
  const float mi2 = minv[row];          // 0 for pad rows
  const float* qrow = q + (size_t)qg * DDIM;
  const float* mrow = mem + (size_t)ra * DDIM;
  float s = 0.f;
  #pragma unroll
  for (int d = 0; d < 16; ++d) {
    int dd = r * 16 + d;
    s += (qrow[dd] * qi) * (mrow[dd] * mi2);
  }
  #pragma unroll
  for (int off = 1; off < 8; off <<= 1) s += __shfl_xor(s, off, 64);  // within 8-group

  // candidate p's exact value + row to lane p
  float myv = __shfl(s, (lane * 8) & 63, 64);
  int mypos = wp[0]; float mypv = wv[0];
  #pragma unroll
  for (int p = 1; p < 8; ++p) {
    mypos = (lane == p) ? wp[p] : mypos;
    mypv  = (lane == p) ? wv[p] : mypv;
  }
  int myrow = decode_row(mypos, mypv);
  if (lane >= 8) { myv = -1e31f; myrow = 0x7fffffff; }

  // 3 selection passes over the 8 exact values (val desc, row asc)
  #pragma unroll
  for (int a = 0; a < 3; ++a) {
    float bv = myv; int bi = myrow;
    #pragma unroll
    for (int off = 32; off >= 1; off >>= 1) {
      float ov = __shfl_xor(bv, off, 64);
      int oi = __shfl_xor(bi, off, 64);
      bool g2 = (ov > bv) || (ov == bv && oi < bi);
      bv = g2 ? ov : bv; bi = g2 ? oi : bi;
    }
    if (lane == 0) {
      out[(size_t)qg * 3 + a] = 1.0f - bv;
      out[(size_t)N_Q * 3 + (size_t)qg * 3 + a] = (float)bi;
    }
    if (myrow == bi) myv = -1e31f;
  }
}

extern "C" void kernel_launch(void* const* d_in, const int* in_sizes, int n_in,
                              void* d_out, int out_size, void* d_ws, size_t ws_size,
                              hipStream_t stream) {
  const float* q = (const float*)d_in[0];
  const float* m = (const float*)d_in[1];

  char* ws = (char*)d_ws;
  size_t off = 0;
  u16* qn = (u16*)(ws + off); off += (size_t)N_Q * DDIM * 2;        // 1 MB
  u16* mn = (u16*)(ws + off); off += (size_t)N_M_PAD * DDIM * 2;    // 25.6 MB
  float* qinv = (float*)(ws + off); off += (size_t)N_Q * 4;
  float* minv = (float*)(ws + off); off += (size_t)N_M_PAD * 4;
  float* pval = (float*)(ws + off); off += (size_t)N_Q * NCAND * 4; // 12.6 MB

  knorm<<<1024, 256, 0, stream>>>(q, m, qn, mn, qinv, minv);
  kgemm<<<NQT * NCHUNK, 256, 0, stream>>>(qn, mn, pval);
  kmerge<<<N_Q / 4, 256, 0, stream>>>(pval, q, m, qinv, minv, (float*)d_out);
}